// Round 3
// baseline (484.972 us; speedup 1.0000x reference)
//
#include <hip/hip_runtime.h>
#include <math.h>
#include <stdint.h>

#define N_NODES 16384
#define N_EDGES 262144
#define HID 128
#define NRBF 20
#define CUTOFF 5.0f
#define PI_F 3.14159265358979323846f

// record layout (28 floats = 112 B, 16B aligned):
// q0=(src,ux,uy,uz) q1=(fcut,c0,c1,c2) q2=(c3..c6) q3=(c7..c10)
// q4=(c11..c14) q5=(c15..c18) q6=(c19,pad,pad,pad)
#define REC_STRIDE 28

__device__ inline unsigned short f2bf(float f) {
    unsigned int u = __float_as_uint(f);
    u = u + 0x7FFFu + ((u >> 16) & 1u);
    return (unsigned short)(u >> 16);
}
__device__ inline uint32_t pack2(float lo, float hi) {
    return (uint32_t)f2bf(lo) | ((uint32_t)f2bf(hi) << 16);
}
__device__ inline float blo(uint32_t u) { return __uint_as_float(u << 16); }
__device__ inline float bhi(uint32_t u) { return __uint_as_float(u & 0xFFFF0000u); }

// ---------------------------------------------------------------------------
// Kernel 1: phi = silu(s@W1+b1)@W2+b2, then pack (phi0,phi1)(phi2,v0)(v1,v2)
// as bf16 pairs into g[node][384] uint32.
// ---------------------------------------------------------------------------
#define NB 16
__global__ __launch_bounds__(128) void phi_kernel(
    const float* __restrict__ s, const float* __restrict__ v,
    const float* __restrict__ W1, const float* __restrict__ b1,
    const float* __restrict__ W2, const float* __restrict__ b2,
    uint32_t* __restrict__ g)
{
    __shared__ float sL[NB][HID];
    __shared__ float hL[NB][HID];
    const int t = threadIdx.x;
    const int node0 = blockIdx.x * NB;

    #pragma unroll
    for (int i = 0; i < NB; ++i)
        sL[i][t] = s[(size_t)(node0 + i) * HID + t];
    __syncthreads();

    float h[NB];
    const float bb1 = b1[t];
    #pragma unroll
    for (int i = 0; i < NB; ++i) h[i] = bb1;

    for (int k = 0; k < HID; k += 4) {
        float w[4];
        #pragma unroll
        for (int j = 0; j < 4; ++j) w[j] = W1[(size_t)(k + j) * HID + t];
        #pragma unroll
        for (int i = 0; i < NB; ++i) {
            const float4 sv = *reinterpret_cast<const float4*>(&sL[i][k]);
            h[i] += sv.x * w[0] + sv.y * w[1] + sv.z * w[2] + sv.w * w[3];
        }
    }
    #pragma unroll
    for (int i = 0; i < NB; ++i) {
        const float x = h[i];
        h[i] = x / (1.0f + expf(-x));
    }
    #pragma unroll
    for (int i = 0; i < NB; ++i) hL[i][t] = h[i];
    __syncthreads();

    float a0[NB], a1[NB], a2[NB];
    #pragma unroll
    for (int i = 0; i < NB; ++i) { a0[i] = 0.f; a1[i] = 0.f; a2[i] = 0.f; }

    for (int k = 0; k < HID; k += 4) {
        float w0[4], w1[4], w2[4];
        #pragma unroll
        for (int j = 0; j < 4; ++j) {
            const size_t row = (size_t)(k + j) * 384;
            w0[j] = W2[row + t];
            w1[j] = W2[row + 128 + t];
            w2[j] = W2[row + 256 + t];
        }
        #pragma unroll
        for (int i = 0; i < NB; ++i) {
            const float4 hv = *reinterpret_cast<const float4*>(&hL[i][k]);
            a0[i] += hv.x * w0[0] + hv.y * w0[1] + hv.z * w0[2] + hv.w * w0[3];
            a1[i] += hv.x * w1[0] + hv.y * w1[1] + hv.z * w1[2] + hv.w * w1[3];
            a2[i] += hv.x * w2[0] + hv.y * w2[1] + hv.z * w2[2] + hv.w * w2[3];
        }
    }
    const float bb2a = b2[t], bb2b = b2[128 + t], bb2c = b2[256 + t];
    #pragma unroll
    for (int i = 0; i < NB; ++i) {
        const size_t nrow = (size_t)(node0 + i) * 384;
        const float p0 = a0[i] + bb2a;
        const float p1 = a1[i] + bb2b;
        const float p2 = a2[i] + bb2c;
        const float v0 = v[nrow + t];
        const float v1 = v[nrow + 128 + t];
        const float v2 = v[nrow + 256 + t];
        g[nrow + t]       = pack2(p0, p1);
        g[nrow + 128 + t] = pack2(p2, v0);
        g[nrow + 256 + t] = pack2(v1, v2);
    }
}

// ---------------------------------------------------------------------------
// CSR build: histogram -> scan -> scatter records
// ---------------------------------------------------------------------------
__global__ __launch_bounds__(256) void hist_kernel(const int* __restrict__ edst,
                                                   int* __restrict__ cnt)
{
    const int e = blockIdx.x * 256 + threadIdx.x;
    if (e < N_EDGES) atomicAdd(&cnt[edst[e]], 1);
}

__global__ __launch_bounds__(256) void scan_kernel(const int* __restrict__ cnt,
                                                   int* __restrict__ row_ptr,
                                                   int* __restrict__ cur)
{
    __shared__ int part[256];
    const int tid = threadIdx.x;
    const int4* c4 = (const int4*)cnt;

    int4 loc[16];
    int s = 0;
    #pragma unroll
    for (int j = 0; j < 16; ++j) {
        loc[j] = c4[tid * 16 + j];
        s += loc[j].x + loc[j].y + loc[j].z + loc[j].w;
    }
    part[tid] = s;
    __syncthreads();
    #pragma unroll
    for (int d = 1; d < 256; d <<= 1) {
        const int add = (tid >= d) ? part[tid - d] : 0;
        __syncthreads();
        part[tid] += add;
        __syncthreads();
    }
    int off = (tid == 0) ? 0 : part[tid - 1];
    const int base = tid * 64;
    #pragma unroll
    for (int j = 0; j < 16; ++j) {
        const int4 q = loc[j];
        row_ptr[base + j*4 + 0] = off; cur[base + j*4 + 0] = off; off += q.x;
        row_ptr[base + j*4 + 1] = off; cur[base + j*4 + 1] = off; off += q.y;
        row_ptr[base + j*4 + 2] = off; cur[base + j*4 + 2] = off; off += q.z;
        row_ptr[base + j*4 + 3] = off; cur[base + j*4 + 3] = off; off += q.w;
    }
    if (tid == 255) row_ptr[16384] = off;
}

__global__ __launch_bounds__(256) void scatter_kernel(
    const float* __restrict__ r_ij, const int* __restrict__ esrc,
    const int* __restrict__ edst, int* __restrict__ cur,
    float* __restrict__ rec)
{
    const int e = blockIdx.x * 256 + threadIdx.x;
    if (e >= N_EDGES) return;
    const float rx = r_ij[(size_t)e * 3 + 0];
    const float ry = r_ij[(size_t)e * 3 + 1];
    const float rz = r_ij[(size_t)e * 3 + 2];
    const float d = sqrtf(rx * rx + ry * ry + rz * rz);
    const float inv_d = 1.0f / d;
    float sx, cx;
    sincosf((PI_F / CUTOFF) * d, &sx, &cx);
    const float fcut = (d < CUTOFF) ? 0.5f * (cx + 1.0f) : 0.0f;

    float cf[NRBF];
    const float gfac = inv_d * fcut;   // fold 1/d and fcut into the rbf coefs
    const float twocx = 2.0f * cx;
    float sm1 = sx, sm2 = 0.0f;
    cf[0] = sx * gfac;
    #pragma unroll
    for (int n = 1; n < NRBF; ++n) {
        const float sn = twocx * sm1 - sm2;
        sm2 = sm1; sm1 = sn;
        cf[n] = sn * gfac;
    }

    const int pos = atomicAdd(&cur[edst[e]], 1);
    float4* r4 = (float4*)(rec + (size_t)pos * REC_STRIDE);
    r4[0] = make_float4(__int_as_float(esrc[e]), rx * inv_d, ry * inv_d, rz * inv_d);
    r4[1] = make_float4(fcut,  cf[0],  cf[1],  cf[2]);
    r4[2] = make_float4(cf[3],  cf[4],  cf[5],  cf[6]);
    r4[3] = make_float4(cf[7],  cf[8],  cf[9],  cf[10]);
    r4[4] = make_float4(cf[11], cf[12], cf[13], cf[14]);
    r4[5] = make_float4(cf[15], cf[16], cf[17], cf[18]);
    r4[6] = make_float4(cf[19], 0.f, 0.f, 0.f);
}

// ---------------------------------------------------------------------------
// Gather: one 128-thread lane-group per node, wr weights pinned in VGPRs,
// 2-edge software pipeline, bf16 packed gathers. No atomics.
// ---------------------------------------------------------------------------
__global__ __launch_bounds__(256) void gather_kernel(
    const uint32_t* __restrict__ g, const float* __restrict__ rec,
    const int* __restrict__ row_ptr, const float* __restrict__ Wrbf,
    const float* __restrict__ brbf,
    float* __restrict__ dv, float* __restrict__ ds)
{
    const int ch   = threadIdx.x & 127;
    const int node = blockIdx.x * 2 + (threadIdx.x >> 7);

    // filter weights: 60 per thread, pinned into VGPRs
    float wr[3 * NRBF];
    #pragma unroll
    for (int n = 0; n < NRBF; ++n) {
        wr[n]            = Wrbf[n * 384 + ch];
        wr[NRBF + n]     = Wrbf[n * 384 + 128 + ch];
        wr[2 * NRBF + n] = Wrbf[n * 384 + 256 + ch];
    }
    #pragma unroll
    for (int n = 0; n < 3 * NRBF; ++n) asm volatile("" : "+v"(wr[n]));

    const float br0 = brbf[ch], br1 = brbf[128 + ch], br2 = brbf[256 + ch];

    const int beg = row_ptr[node];
    const int end = row_ptr[node + 1];

    float a0 = 0.f, a1 = 0.f, a2 = 0.f, asum = 0.f;

    int i = beg;
    for (; i + 1 < end; i += 2) {
        const float* ra = rec + (size_t)i * REC_STRIDE;
        const float* rb = rec + (size_t)(i + 1) * REC_STRIDE;
        const float4 qa0 = *(const float4*)ra;
        const float4 qb0 = *(const float4*)rb;
        const uint32_t* ga = g + (size_t)__float_as_int(qa0.x) * 384 + ch;
        const uint32_t* gb = g + (size_t)__float_as_int(qb0.x) * 384 + ch;
        const uint32_t pa0 = ga[0], pa1 = ga[128], pa2 = ga[256];
        const uint32_t pb0 = gb[0], pb1 = gb[128], pb2 = gb[256];

        const float4 qa1 = *(const float4*)(ra + 4);
        const float4 qa2 = *(const float4*)(ra + 8);
        const float4 qa3 = *(const float4*)(ra + 12);
        const float4 qa4 = *(const float4*)(ra + 16);
        const float4 qa5 = *(const float4*)(ra + 20);
        const float ca19 = ra[24];
        const float4 qb1 = *(const float4*)(rb + 4);
        const float4 qb2 = *(const float4*)(rb + 8);
        const float4 qb3 = *(const float4*)(rb + 12);
        const float4 qb4 = *(const float4*)(rb + 16);
        const float4 qb5 = *(const float4*)(rb + 20);
        const float cb19 = rb[24];

        const float ca[NRBF] = { qa1.y, qa1.z, qa1.w, qa2.x, qa2.y, qa2.z,
                                 qa2.w, qa3.x, qa3.y, qa3.z, qa3.w, qa4.x,
                                 qa4.y, qa4.z, qa4.w, qa5.x, qa5.y, qa5.z,
                                 qa5.w, ca19 };
        const float cb[NRBF] = { qb1.y, qb1.z, qb1.w, qb2.x, qb2.y, qb2.z,
                                 qb2.w, qb3.x, qb3.y, qb3.z, qb3.w, qb4.x,
                                 qb4.y, qb4.z, qb4.w, qb5.x, qb5.y, qb5.z,
                                 qb5.w, cb19 };

        float W0a = br0 * qa1.x, W1a = br1 * qa1.x, W2a = br2 * qa1.x;
        float W0b = br0 * qb1.x, W1b = br1 * qb1.x, W2b = br2 * qb1.x;
        #pragma unroll
        for (int n = 0; n < NRBF; ++n) {
            W0a += ca[n] * wr[n];
            W1a += ca[n] * wr[NRBF + n];
            W2a += ca[n] * wr[2 * NRBF + n];
            W0b += cb[n] * wr[n];
            W1b += cb[n] * wr[NRBF + n];
            W2b += cb[n] * wr[2 * NRBF + n];
        }

        const float xva = blo(pa0) * W0a;
        const float xsa = bhi(pa0) * W1a;
        const float xda = blo(pa1) * W2a;
        a0   += bhi(pa1) * xva + qa0.y * xda;
        a1   += blo(pa2) * xva + qa0.z * xda;
        a2   += bhi(pa2) * xva + qa0.w * xda;
        asum += xsa;

        const float xvb = blo(pb0) * W0b;
        const float xsb = bhi(pb0) * W1b;
        const float xdb = blo(pb1) * W2b;
        a0   += bhi(pb1) * xvb + qb0.y * xdb;
        a1   += blo(pb2) * xvb + qb0.z * xdb;
        a2   += bhi(pb2) * xvb + qb0.w * xdb;
        asum += xsb;
    }
    if (i < end) {
        const float* ra = rec + (size_t)i * REC_STRIDE;
        const float4 qa0 = *(const float4*)ra;
        const uint32_t* ga = g + (size_t)__float_as_int(qa0.x) * 384 + ch;
        const uint32_t pa0 = ga[0], pa1 = ga[128], pa2 = ga[256];
        const float4 qa1 = *(const float4*)(ra + 4);
        const float4 qa2 = *(const float4*)(ra + 8);
        const float4 qa3 = *(const float4*)(ra + 12);
        const float4 qa4 = *(const float4*)(ra + 16);
        const float4 qa5 = *(const float4*)(ra + 20);
        const float ca19 = ra[24];
        const float ca[NRBF] = { qa1.y, qa1.z, qa1.w, qa2.x, qa2.y, qa2.z,
                                 qa2.w, qa3.x, qa3.y, qa3.z, qa3.w, qa4.x,
                                 qa4.y, qa4.z, qa4.w, qa5.x, qa5.y, qa5.z,
                                 qa5.w, ca19 };
        float W0a = br0 * qa1.x, W1a = br1 * qa1.x, W2a = br2 * qa1.x;
        #pragma unroll
        for (int n = 0; n < NRBF; ++n) {
            W0a += ca[n] * wr[n];
            W1a += ca[n] * wr[NRBF + n];
            W2a += ca[n] * wr[2 * NRBF + n];
        }
        const float xva = blo(pa0) * W0a;
        const float xsa = bhi(pa0) * W1a;
        const float xda = blo(pa1) * W2a;
        a0   += bhi(pa1) * xva + qa0.y * xda;
        a1   += blo(pa2) * xva + qa0.z * xda;
        a2   += bhi(pa2) * xva + qa0.w * xda;
        asum += xsa;
    }

    const size_t orow = (size_t)node * 384;
    dv[orow + ch]       = a0;
    dv[orow + 128 + ch] = a1;
    dv[orow + 256 + ch] = a2;
    ds[(size_t)node * HID + ch] = asum;
}

extern "C" void kernel_launch(void* const* d_in, const int* in_sizes, int n_in,
                              void* d_out, int out_size, void* d_ws, size_t ws_size,
                              hipStream_t stream)
{
    const float* s    = (const float*)d_in[0];
    const float* v    = (const float*)d_in[1];
    const float* r_ij = (const float*)d_in[2];
    const int*   esrc = (const int*)d_in[3];
    const int*   edst = (const int*)d_in[4];
    const float* W1   = (const float*)d_in[5];
    const float* b1   = (const float*)d_in[6];
    const float* W2   = (const float*)d_in[7];
    const float* b2   = (const float*)d_in[8];
    const float* Wrbf = (const float*)d_in[9];
    const float* brbf = (const float*)d_in[10];

    float* out = (float*)d_out;
    float* dv  = out;                                   // (16384,3,128)
    float* ds  = out + (size_t)N_NODES * 3 * HID;       // (16384,128)

    char* ws = (char*)d_ws;
    uint32_t* g       = (uint32_t*)(ws + 0);            // 25,165,824 B
    float*    rec     = (float*)   (ws + 25165824);     // 29,360,128 B
    int*      cnt     = (int*)     (ws + 54525952);     // 65,536 B
    int*      row_ptr = (int*)     (ws + 54591488);     // 65,540 B (+pad)
    int*      cur     = (int*)     (ws + 54657152);     // 65,536 B

    hipMemsetAsync(cnt, 0, 16384 * sizeof(int), stream);

    phi_kernel<<<N_NODES / NB, 128, 0, stream>>>(s, v, W1, b1, W2, b2, g);
    hist_kernel<<<N_EDGES / 256, 256, 0, stream>>>(edst, cnt);
    scan_kernel<<<1, 256, 0, stream>>>(cnt, row_ptr, cur);
    scatter_kernel<<<N_EDGES / 256, 256, 0, stream>>>(r_ij, esrc, edst, cur, rec);
    gather_kernel<<<N_NODES / 2, 256, 0, stream>>>(g, rec, row_ptr, Wrbf, brbf,
                                                   dv, ds);
}

// Round 5
// 225.853 us; speedup vs baseline: 2.1473x; 2.1473x over previous
//
#include <hip/hip_runtime.h>
#include <math.h>
#include <stdint.h>

#define N_NODES 16384
#define N_EDGES 262144
#define HID 128
#define NRBF 20
#define CUTOFF 5.0f
#define PI_F 3.14159265358979323846f

// coef record: 24 floats = 96 B: [0..2]=ux,uy,uz [3]=fcut [4..23]=c0..c19
#define CSTRIDE 24

__device__ inline unsigned short f2bf(float f) {
    unsigned int u = __float_as_uint(f);
    u = u + 0x7FFFu + ((u >> 16) & 1u);
    return (unsigned short)(u >> 16);
}
__device__ inline uint32_t pack2(float lo, float hi) {
    return (uint32_t)f2bf(lo) | ((uint32_t)f2bf(hi) << 16);
}
__device__ inline float blo(uint32_t u) { return __uint_as_float(u << 16); }
__device__ inline float bhi(uint32_t u) { return __uint_as_float(u & 0xFFFF0000u); }

// ---------------------------------------------------------------------------
// Kernel 1: phi = silu(s@W1+b1)@W2+b2, packed with v as bf16 pairs into
// g[node][384]: (phi0,phi1)(phi2,v0)(v1,v2)
// ---------------------------------------------------------------------------
#define NB 16
__global__ __launch_bounds__(128) void phi_kernel(
    const float* __restrict__ s, const float* __restrict__ v,
    const float* __restrict__ W1, const float* __restrict__ b1,
    const float* __restrict__ W2, const float* __restrict__ b2,
    uint32_t* __restrict__ g)
{
    __shared__ float sL[NB][HID];
    __shared__ float hL[NB][HID];
    const int t = threadIdx.x;
    const int node0 = blockIdx.x * NB;

    #pragma unroll
    for (int i = 0; i < NB; ++i)
        sL[i][t] = s[(size_t)(node0 + i) * HID + t];
    __syncthreads();

    float h[NB];
    const float bb1 = b1[t];
    #pragma unroll
    for (int i = 0; i < NB; ++i) h[i] = bb1;

    for (int k = 0; k < HID; k += 4) {
        float w[4];
        #pragma unroll
        for (int j = 0; j < 4; ++j) w[j] = W1[(size_t)(k + j) * HID + t];
        #pragma unroll
        for (int i = 0; i < NB; ++i) {
            const float4 sv = *reinterpret_cast<const float4*>(&sL[i][k]);
            h[i] += sv.x * w[0] + sv.y * w[1] + sv.z * w[2] + sv.w * w[3];
        }
    }
    #pragma unroll
    for (int i = 0; i < NB; ++i) {
        const float x = h[i];
        h[i] = x / (1.0f + expf(-x));
    }
    #pragma unroll
    for (int i = 0; i < NB; ++i) hL[i][t] = h[i];
    __syncthreads();

    float a0[NB], a1[NB], a2[NB];
    #pragma unroll
    for (int i = 0; i < NB; ++i) { a0[i] = 0.f; a1[i] = 0.f; a2[i] = 0.f; }

    for (int k = 0; k < HID; k += 4) {
        float w0[4], w1[4], w2[4];
        #pragma unroll
        for (int j = 0; j < 4; ++j) {
            const size_t row = (size_t)(k + j) * 384;
            w0[j] = W2[row + t];
            w1[j] = W2[row + 128 + t];
            w2[j] = W2[row + 256 + t];
        }
        #pragma unroll
        for (int i = 0; i < NB; ++i) {
            const float4 hv = *reinterpret_cast<const float4*>(&hL[i][k]);
            a0[i] += hv.x * w0[0] + hv.y * w0[1] + hv.z * w0[2] + hv.w * w0[3];
            a1[i] += hv.x * w1[0] + hv.y * w1[1] + hv.z * w1[2] + hv.w * w1[3];
            a2[i] += hv.x * w2[0] + hv.y * w2[1] + hv.z * w2[2] + hv.w * w2[3];
        }
    }
    const float bb2a = b2[t], bb2b = b2[128 + t], bb2c = b2[256 + t];
    #pragma unroll
    for (int i = 0; i < NB; ++i) {
        const size_t nrow = (size_t)(node0 + i) * 384;
        const float p0 = a0[i] + bb2a;
        const float p1 = a1[i] + bb2b;
        const float p2 = a2[i] + bb2c;
        const float v0 = v[nrow + t];
        const float v1 = v[nrow + 128 + t];
        const float v2 = v[nrow + 256 + t];
        g[nrow + t]       = pack2(p0, p1);
        g[nrow + 128 + t] = pack2(p2, v0);
        g[nrow + 256 + t] = pack2(v1, v2);
    }
}

// ---------------------------------------------------------------------------
// CSR build: histogram -> scan -> scatter (SoA: srcs[] + coef[])
// ---------------------------------------------------------------------------
__global__ __launch_bounds__(256) void hist_kernel(const int* __restrict__ edst,
                                                   int* __restrict__ cnt)
{
    const int e = blockIdx.x * 256 + threadIdx.x;
    if (e < N_EDGES) atomicAdd(&cnt[edst[e]], 1);
}

__global__ __launch_bounds__(256) void scan_kernel(const int* __restrict__ cnt,
                                                   int* __restrict__ row_ptr,
                                                   int* __restrict__ cur)
{
    __shared__ int part[256];
    const int tid = threadIdx.x;
    const int4* c4 = (const int4*)cnt;

    int4 loc[16];
    int s = 0;
    #pragma unroll
    for (int j = 0; j < 16; ++j) {
        loc[j] = c4[tid * 16 + j];
        s += loc[j].x + loc[j].y + loc[j].z + loc[j].w;
    }
    part[tid] = s;
    __syncthreads();
    #pragma unroll
    for (int d = 1; d < 256; d <<= 1) {
        const int add = (tid >= d) ? part[tid - d] : 0;
        __syncthreads();
        part[tid] += add;
        __syncthreads();
    }
    int off = (tid == 0) ? 0 : part[tid - 1];
    const int base = tid * 64;
    #pragma unroll
    for (int j = 0; j < 16; ++j) {
        const int4 q = loc[j];
        row_ptr[base + j*4 + 0] = off; cur[base + j*4 + 0] = off; off += q.x;
        row_ptr[base + j*4 + 1] = off; cur[base + j*4 + 1] = off; off += q.y;
        row_ptr[base + j*4 + 2] = off; cur[base + j*4 + 2] = off; off += q.z;
        row_ptr[base + j*4 + 3] = off; cur[base + j*4 + 3] = off; off += q.w;
    }
    if (tid == 255) row_ptr[16384] = off;
}

__global__ __launch_bounds__(256) void scatter_kernel(
    const float* __restrict__ r_ij, const int* __restrict__ esrc,
    const int* __restrict__ edst, int* __restrict__ cur,
    int* __restrict__ srcs, float* __restrict__ coef)
{
    const int e = blockIdx.x * 256 + threadIdx.x;
    if (e >= N_EDGES) return;
    const float rx = r_ij[(size_t)e * 3 + 0];
    const float ry = r_ij[(size_t)e * 3 + 1];
    const float rz = r_ij[(size_t)e * 3 + 2];
    const float d = sqrtf(rx * rx + ry * ry + rz * rz);
    const float inv_d = 1.0f / d;
    float sx, cx;
    sincosf((PI_F / CUTOFF) * d, &sx, &cx);
    const float fcut = (d < CUTOFF) ? 0.5f * (cx + 1.0f) : 0.0f;

    float cf[NRBF];
    const float gfac = inv_d * fcut;
    const float twocx = 2.0f * cx;
    float sm1 = sx, sm2 = 0.0f;
    cf[0] = sx * gfac;
    #pragma unroll
    for (int n = 1; n < NRBF; ++n) {
        const float sn = twocx * sm1 - sm2;
        sm2 = sm1; sm1 = sn;
        cf[n] = sn * gfac;
    }

    const int pos = atomicAdd(&cur[edst[e]], 1);
    srcs[pos] = esrc[e];
    float4* c4 = (float4*)(coef + (size_t)pos * CSTRIDE);
    c4[0] = make_float4(rx * inv_d, ry * inv_d, rz * inv_d, fcut);
    c4[1] = make_float4(cf[0],  cf[1],  cf[2],  cf[3]);
    c4[2] = make_float4(cf[4],  cf[5],  cf[6],  cf[7]);
    c4[3] = make_float4(cf[8],  cf[9],  cf[10], cf[11]);
    c4[4] = make_float4(cf[12], cf[13], cf[14], cf[15]);
    c4[5] = make_float4(cf[16], cf[17], cf[18], cf[19]);
}

// ---------------------------------------------------------------------------
// Gather: node per 128-thread group; batch-4 edges; double-buffered gather
// loads issued a full batch ahead; scalar (readfirstlane) coef/src loads.
// ---------------------------------------------------------------------------
__global__ __launch_bounds__(256, 4) void gather_kernel(
    const uint32_t* __restrict__ gbuf, const int* __restrict__ srcs,
    const float* __restrict__ coef, const int* __restrict__ row_ptr,
    const float* __restrict__ Wrbf, const float* __restrict__ brbf,
    float* __restrict__ dv, float* __restrict__ ds)
{
    const int ch   = threadIdx.x & 127;
    const int node = blockIdx.x * 2 + (threadIdx.x >> 7);

    // filter weights (+ bias as 21st row), target: resident in VGPRs
    float wr0[NRBF + 1], wr1[NRBF + 1], wr2[NRBF + 1];
    #pragma unroll
    for (int n = 0; n < NRBF; ++n) {
        wr0[n] = Wrbf[n * 384 + ch];
        wr1[n] = Wrbf[n * 384 + 128 + ch];
        wr2[n] = Wrbf[n * 384 + 256 + ch];
    }
    wr0[NRBF] = brbf[ch];
    wr1[NRBF] = brbf[128 + ch];
    wr2[NRBF] = brbf[256 + ch];

    const int beg = row_ptr[node];
    const int end = row_ptr[node + 1];
    const int nb  = (end - beg) >> 2;

    float a0 = 0.f, a1 = 0.f, a2 = 0.f, as = 0.f;

    uint32_t pc[12];
    if (nb > 0) {
        const int* sp = srcs + __builtin_amdgcn_readfirstlane(beg);
        const int s0 = sp[0], s1 = sp[1], s2 = sp[2], s3 = sp[3];
        const uint32_t* g0 = gbuf + (size_t)s0 * 384 + ch;
        const uint32_t* g1 = gbuf + (size_t)s1 * 384 + ch;
        const uint32_t* g2 = gbuf + (size_t)s2 * 384 + ch;
        const uint32_t* g3 = gbuf + (size_t)s3 * 384 + ch;
        pc[0] = g0[0]; pc[1]  = g0[128]; pc[2]  = g0[256];
        pc[3] = g1[0]; pc[4]  = g1[128]; pc[5]  = g1[256];
        pc[6] = g2[0]; pc[7]  = g2[128]; pc[8]  = g2[256];
        pc[9] = g3[0]; pc[10] = g3[128]; pc[11] = g3[256];
    }

    for (int b = 0; b < nb; ++b) {
        const int i4 = beg + b * 4;

        // issue NEXT batch's gather loads before consuming current
        uint32_t pn[12];
        {
            const int ii = (b + 1 < nb) ? (i4 + 4) : i4;
            const int* sp = srcs + __builtin_amdgcn_readfirstlane(ii);
            const int t0 = sp[0], t1 = sp[1], t2 = sp[2], t3 = sp[3];
            const uint32_t* h0 = gbuf + (size_t)t0 * 384 + ch;
            const uint32_t* h1 = gbuf + (size_t)t1 * 384 + ch;
            const uint32_t* h2 = gbuf + (size_t)t2 * 384 + ch;
            const uint32_t* h3 = gbuf + (size_t)t3 * 384 + ch;
            pn[0] = h0[0]; pn[1]  = h0[128]; pn[2]  = h0[256];
            pn[3] = h1[0]; pn[4]  = h1[128]; pn[5]  = h1[256];
            pn[6] = h2[0]; pn[7]  = h2[128]; pn[8]  = h2[256];
            pn[9] = h3[0]; pn[10] = h3[128]; pn[11] = h3[256];
        }

        const float* cp = coef + (size_t)__builtin_amdgcn_readfirstlane(i4) * CSTRIDE;
        #pragma unroll
        for (int k = 0; k < 4; ++k) {
            const float ux = cp[k * CSTRIDE + 0];
            const float uy = cp[k * CSTRIDE + 1];
            const float uz = cp[k * CSTRIDE + 2];
            const float fc = cp[k * CSTRIDE + 3];
            float W0 = fc * wr0[NRBF];
            float W1 = fc * wr1[NRBF];
            float W2 = fc * wr2[NRBF];
            #pragma unroll
            for (int n = 0; n < NRBF; ++n) {
                const float c = cp[k * CSTRIDE + 4 + n];
                W0 += c * wr0[n];
                W1 += c * wr1[n];
                W2 += c * wr2[n];
            }
            const uint32_t p0 = pc[k * 3], p1 = pc[k * 3 + 1], p2 = pc[k * 3 + 2];
            const float xv = blo(p0) * W0;
            const float xs = bhi(p0) * W1;
            const float xd = blo(p1) * W2;
            a0 += bhi(p1) * xv + ux * xd;
            a1 += blo(p2) * xv + uy * xd;
            a2 += bhi(p2) * xv + uz * xd;
            as += xs;
        }
        #pragma unroll
        for (int j = 0; j < 12; ++j) pc[j] = pn[j];
    }

    // tail (0..3 edges)
    for (int i = beg + (nb << 2); i < end; ++i) {
        const int s = srcs[i];
        const uint32_t* gg = gbuf + (size_t)s * 384 + ch;
        const uint32_t p0 = gg[0], p1 = gg[128], p2 = gg[256];
        const float* cp = coef + (size_t)__builtin_amdgcn_readfirstlane(i) * CSTRIDE;
        const float ux = cp[0], uy = cp[1], uz = cp[2], fc = cp[3];
        float W0 = fc * wr0[NRBF];
        float W1 = fc * wr1[NRBF];
        float W2 = fc * wr2[NRBF];
        #pragma unroll
        for (int n = 0; n < NRBF; ++n) {
            const float c = cp[4 + n];
            W0 += c * wr0[n];
            W1 += c * wr1[n];
            W2 += c * wr2[n];
        }
        const float xv = blo(p0) * W0;
        const float xs = bhi(p0) * W1;
        const float xd = blo(p1) * W2;
        a0 += bhi(p1) * xv + ux * xd;
        a1 += blo(p2) * xv + uy * xd;
        a2 += bhi(p2) * xv + uz * xd;
        as += xs;
    }

    const size_t orow = (size_t)node * 384;
    dv[orow + ch]       = a0;
    dv[orow + 128 + ch] = a1;
    dv[orow + 256 + ch] = a2;
    ds[(size_t)node * HID + ch] = as;
}

extern "C" void kernel_launch(void* const* d_in, const int* in_sizes, int n_in,
                              void* d_out, int out_size, void* d_ws, size_t ws_size,
                              hipStream_t stream)
{
    const float* s    = (const float*)d_in[0];
    const float* v    = (const float*)d_in[1];
    const float* r_ij = (const float*)d_in[2];
    const int*   esrc = (const int*)d_in[3];
    const int*   edst = (const int*)d_in[4];
    const float* W1   = (const float*)d_in[5];
    const float* b1   = (const float*)d_in[6];
    const float* W2   = (const float*)d_in[7];
    const float* b2   = (const float*)d_in[8];
    const float* Wrbf = (const float*)d_in[9];
    const float* brbf = (const float*)d_in[10];

    float* out = (float*)d_out;
    float* dv  = out;                                   // (16384,3,128)
    float* ds  = out + (size_t)N_NODES * 3 * HID;       // (16384,128)

    // workspace layout — row_ptr gets 65,536 + 128 B so row_ptr[16384]
    // (written by scan) can NOT alias cur[0] (the R4 crash).
    char* ws = (char*)d_ws;
    uint32_t* g       = (uint32_t*)(ws + 0);            // 25,165,824 B
    float*    coef    = (float*)   (ws + 25165824);     // 25,165,824 B
    int*      srcs    = (int*)     (ws + 50331648);     //  1,048,576 B
    int*      cnt     = (int*)     (ws + 51380224);     //     65,536 B
    int*      row_ptr = (int*)     (ws + 51445760);     //     65,540 B used
    int*      cur     = (int*)     (ws + 51511424);     //     65,536 B (128B pad before)

    hipMemsetAsync(cnt, 0, 16384 * sizeof(int), stream);

    phi_kernel<<<N_NODES / NB, 128, 0, stream>>>(s, v, W1, b1, W2, b2, g);
    hist_kernel<<<N_EDGES / 256, 256, 0, stream>>>(edst, cnt);
    scan_kernel<<<1, 256, 0, stream>>>(cnt, row_ptr, cur);
    scatter_kernel<<<N_EDGES / 256, 256, 0, stream>>>(r_ij, esrc, edst, cur,
                                                      srcs, coef);
    gather_kernel<<<N_NODES / 2, 256, 0, stream>>>(g, srcs, coef, row_ptr,
                                                   Wrbf, brbf, dv, ds);
}